// Round 17
// baseline (423.186 us; speedup 1.0000x reference)
//
#include <hip/hip_runtime.h>

typedef __bf16 bf16x8 __attribute__((ext_vector_type(8)));
typedef __bf16 bf16x4 __attribute__((ext_vector_type(4)));
typedef float f32x4 __attribute__((ext_vector_type(4)));

constexpr int Sq = 2048, Dd = 1024, Hn = 16, Pn = 10, DK = 64;
constexpr int SKPAD = 2112;   // key axis: [0,2048) seq, [2048,2058) prefix, pad to 2112
constexpr int NBH = 64;       // B*H
constexpr float LOG2E = 1.44269504088896340736f;

__device__ __forceinline__ float exp2_fast(float x) {
  return __builtin_amdgcn_exp2f(x);  // v_exp_f32 computes 2^x natively
}

__device__ __forceinline__ unsigned short f2bf(float f) {
  unsigned int u = __float_as_uint(f);
  u += 0x7fffu + ((u >> 16) & 1u);   // RNE
  return (unsigned short)(u >> 16);
}

__device__ __forceinline__ void gload_lds16(const void* g, void* l) {
  __builtin_amdgcn_global_load_lds(
      (const __attribute__((address_space(1))) void*)g,
      (__attribute__((address_space(3))) void*)l, 16, 0, 0);
}

__device__ __forceinline__ f32x4 mfma16(bf16x8 a, bf16x8 b, f32x4 c) {
  return __builtin_amdgcn_mfma_f32_16x16x32_bf16(a, b, c, 0, 0, 0);
}

// ---------------- W transpose + convert: Wt[n][k] = W[k][n] ----------------
__global__ void k_wt(const float* __restrict__ W0, const float* __restrict__ W1,
                     const float* __restrict__ W2, const float* __restrict__ W3,
                     unsigned short* __restrict__ T0, unsigned short* __restrict__ T1,
                     unsigned short* __restrict__ T2, unsigned short* __restrict__ T3) {
  __shared__ float tile[32][33];
  const float* W; unsigned short* T;
  switch (blockIdx.z) {
    case 0: W = W0; T = T0; break;
    case 1: W = W1; T = T1; break;
    case 2: W = W2; T = T2; break;
    default: W = W3; T = T3; break;
  }
  int n0 = blockIdx.x * 32, k0 = blockIdx.y * 32;
  int tx = threadIdx.x, ty = threadIdx.y;
  for (int r = ty; r < 32; r += 8)
    tile[r][tx] = W[(size_t)(k0 + r) * Dd + n0 + tx];
  __syncthreads();
  for (int r = ty; r < 32; r += 8)
    T[(size_t)(n0 + r) * Dd + k0 + tx] = f2bf(tile[tx][r]);
}

// ---------------- prefix K/V fill (at key slots 2048..2057) + zero pad -------
__global__ void k_fill(const float* __restrict__ pk, const float* __restrict__ pv,
                       unsigned short* __restrict__ Kb, unsigned short* __restrict__ Vt) {
  int bh = blockIdx.x;
  int h = bh & (Hn - 1);
  unsigned short* Kbh = Kb + (size_t)bh * SKPAD * DK;
  unsigned short* Vth = Vt + (size_t)bh * DK * SKPAD;
  for (int i = threadIdx.x; i < Pn * DK; i += blockDim.x) {
    int p = i >> 6, dk = i & 63;
    float kv = pk[((size_t)h * Pn + p) * DK + dk];
    float vv = pv[((size_t)h * Pn + p) * DK + dk];
    Kbh[(Sq + p) * DK + dk] = f2bf(kv);
    Vth[(size_t)dk * SKPAD + Sq + p] = f2bf(vv);
  }
  constexpr int ZR = SKPAD - (Pn + Sq);  // 54 zero rows/cols
  for (int i = threadIdx.x; i < ZR * DK; i += blockDim.x) {
    int r = i >> 6, c = i & 63;
    Kbh[(Sq + Pn + r) * DK + c] = 0;
    Vth[(size_t)c * SKPAD + (Sq + Pn + r)] = 0;
  }
}

// ---------------- QKV GEMM: C[8192,1024] = A_f32 @ Bt^T + bias ----------------
// R9 A-path (fp32 via global_load_lds into 32 KB swizzled LDS, fp32->bf16 fused
// into the fragment path). B (weights, L2-hot per XCD) loaded to REGISTERS,
// issued immediately after A's DMA so B's L2 latency is paid concurrently with
// A's drain (fixes R14's post-barrier serialization). LDS 32 KB -> 4 blocks/CU.
// stream 0: Q -> [B,H,S,DK] (scale folded)   stream 1: K -> [B,H,SKPAD,DK]
// stream 2: V -> [B,H,DK,SKPAD] transposed, stored via LDS transpose.
__global__ __launch_bounds__(256, 4) void k_gemm_qkv(
    const float* __restrict__ Aq, const float* __restrict__ Ak,
    const float* __restrict__ Av,
    const unsigned short* __restrict__ Wq, const unsigned short* __restrict__ Wk,
    const unsigned short* __restrict__ Wv,
    const float* __restrict__ bq, const float* __restrict__ bk,
    const float* __restrict__ bv,
    unsigned short* __restrict__ Qo, unsigned short* __restrict__ Ko,
    unsigned short* __restrict__ Vo, float qscale) {
  __shared__ float Af[128 * 64];            // 32 KB fp32 A tile (swizzled)
  int bx0 = blockIdx.x;                     // 0..1535
  int orig = (bx0 & 7) * 192 + (bx0 >> 3);  // bijective XCD-chunked swizzle
  int stream = orig >> 9, within = orig & 511;

  const float* A32; const unsigned short* Bt; const float* bias;
  unsigned short* outB; float scale;
  switch (stream) {
    case 0:  A32 = Aq; Bt = Wq; bias = bq; outB = Qo; scale = qscale; break;
    case 1:  A32 = Ak; Bt = Wk; bias = bk; outB = Ko; scale = 1.f; break;
    default: A32 = Av; Bt = Wv; bias = bv; outB = Vo; scale = 1.f; break;
  }

  int tid = threadIdx.x;
  int w = tid >> 6, l = tid & 63;
  int lq = l & 15, lg = l >> 4;
  int tm = within >> 3, tn = within & 7;
  int brow = tm * 128, bcol = tn * 128;
  int wm = w >> 1, wn = w & 1;

  f32x4 acc[4][4];
#pragma unroll
  for (int m = 0; m < 4; ++m)
#pragma unroll
    for (int n = 0; n < 4; ++n) acc[m][n] = (f32x4){0.f, 0.f, 0.f, 0.f};

  // wave-fixed B fragment base rows
  const unsigned short* Brow[4];
#pragma unroll
  for (int n = 0; n < 4; ++n)
    Brow[n] = Bt + (size_t)(bcol + wn * 64 + n * 16 + lq) * 1024;

  for (int kt = 0; kt < 1024; kt += 64) {
    // A fp32: 8 chunks of 16B/lane; LDS linear, global source pre-swizzled
#pragma unroll
    for (int it = 0; it < 8; ++it) {
      int c = it * 256 + tid;
      int row = c >> 4;
      int cb = (c & 15) * 16;                    // byte-in-row (256 B rows)
      int sb = cb ^ ((row & 7) << 4);
      gload_lds16((const char*)(A32 + (size_t)(brow + row) * 1024 + kt) + sb,
                  (char*)Af + (size_t)(it * 256 + w * 64) * 16);
    }
    // B fragments to registers (L2-hit; latency shared with A's DMA drain)
    bf16x8 bfv[2][4];
#pragma unroll
    for (int ks = 0; ks < 2; ++ks)
#pragma unroll
      for (int n = 0; n < 4; ++n)
        bfv[ks][n] = *reinterpret_cast<const bf16x8*>(
            Brow[n] + kt + ks * 32 + lg * 8);
    asm volatile("s_waitcnt vmcnt(0)" ::: "memory");
    __syncthreads();
#pragma unroll
    for (int ks = 0; ks < 2; ++ks) {
      bf16x8 af[4];
#pragma unroll
      for (int m = 0; m < 4; ++m) {
        int row = wm * 64 + m * 16 + lq;
        int b0 = row * 256 + ks * 128 + lg * 32;
        int sw = (row & 7) << 4;
        f32x4 a0 = *reinterpret_cast<const f32x4*>((const char*)Af + (b0 ^ sw));
        f32x4 a1 = *reinterpret_cast<const f32x4*>((const char*)Af + ((b0 + 16) ^ sw));
        bf16x8 v;
        v[0] = (__bf16)a0[0]; v[1] = (__bf16)a0[1];
        v[2] = (__bf16)a0[2]; v[3] = (__bf16)a0[3];
        v[4] = (__bf16)a1[0]; v[5] = (__bf16)a1[1];
        v[6] = (__bf16)a1[2]; v[7] = (__bf16)a1[3];
        af[m] = v;
      }
#pragma unroll
      for (int m = 0; m < 4; ++m)
#pragma unroll
        for (int n = 0; n < 4; ++n)
          acc[m][n] = mfma16(af[m], bfv[ks][n], acc[m][n]);
    }
    __syncthreads();
  }

  if (stream < 2) {
#pragma unroll
    for (int n = 0; n < 4; ++n) {
      int N = bcol + wn * 64 + n * 16 + lq;
      float bv = bias[N];
#pragma unroll
      for (int m = 0; m < 4; ++m) {
        int M0 = brow + wm * 64 + m * 16 + lg * 4;
#pragma unroll
        for (int r = 0; r < 4; ++r) {
          float val = (acc[m][n][r] + bv) * scale;
          int Mr = M0 + r;
          int b = Mr >> 11, s = Mr & 2047;
          int h = N >> 6, dk = N & 63;
          size_t idx;
          if (stream == 0) idx = (((size_t)(b * Hn + h)) * Sq + s) * DK + dk;
          else             idx = (((size_t)(b * Hn + h)) * SKPAD + s) * DK + dk;
          outB[idx] = f2bf(val);
        }
      }
    }
  } else {
    // V: transpose 128x128 tile through LDS, then coalesced 16B row stores.
    __syncthreads();                    // all LDS reads of Af done
    unsigned short* T = (unsigned short*)Af;  // 32 KB: [col(dv)][row(s)] xor-swz
#pragma unroll
    for (int n = 0; n < 4; ++n) {
      int col = wn * 64 + n * 16 + lq;
      float bv = bias[bcol + col];
      int sw = (col & 7) << 4;
#pragma unroll
      for (int m = 0; m < 4; ++m) {
        int row0 = wm * 64 + m * 16 + lg * 4;
        ushort4 p4;
        p4.x = f2bf(acc[m][n][0] + bv);
        p4.y = f2bf(acc[m][n][1] + bv);
        p4.z = f2bf(acc[m][n][2] + bv);
        p4.w = f2bf(acc[m][n][3] + bv);
        *reinterpret_cast<ushort4*>(&T[col * 128 + (row0 ^ sw)]) = p4;
      }
    }
    __syncthreads();
    int b = brow >> 11, s0 = brow & 2047;
    int col = tid >> 1;                 // dv index within block (0..127)
    int off = (tid & 1) * 64;           // s offset (0 or 64)
    int sw = (col & 7) << 4;
    int h = (bcol + col) >> 6, dk = (bcol + col) & 63;
    unsigned short* dst = Vo + (((size_t)(b * Hn + h)) * DK + dk) * SKPAD + s0 + off;
#pragma unroll
    for (int j = 0; j < 8; ++j) {
      int4 v = *reinterpret_cast<const int4*>(&T[col * 128 + ((off + j * 8) ^ sw)]);
      *reinterpret_cast<int4*>(dst + j * 8) = v;
    }
  }
}

// ---------------- O GEMM: out[8192,1024] = Ob @ Wot^T + bo (fp32 out) -------
// 64x128 tile: grid 1024 -> 4 blocks/CU. Both operands via global_load_lds,
// 24 KB LDS, 2-barrier template.
__global__ __launch_bounds__(256, 4) void k_gemm_o(
    const unsigned short* __restrict__ A, const unsigned short* __restrict__ Bt,
    const float* __restrict__ bias, float* __restrict__ outF) {
  __shared__ unsigned short As[64 * 64];     // 8 KB
  __shared__ unsigned short Bs[128 * 64];    // 16 KB
  int bx0 = blockIdx.x;                      // 0..1023
  int within = (bx0 & 7) * 128 + (bx0 >> 3); // bijective XCD-chunked swizzle
  int tid = threadIdx.x;
  int w = tid >> 6, l = tid & 63;
  int lq = l & 15, lg = l >> 4;
  int tm = within >> 3, tn = within & 7;
  int brow = tm * 64, bcol = tn * 128;
  int wm = w >> 1, wn = w & 1;

  f32x4 acc[2][4];
#pragma unroll
  for (int m = 0; m < 2; ++m)
#pragma unroll
    for (int n = 0; n < 4; ++n) acc[m][n] = (f32x4){0.f, 0.f, 0.f, 0.f};

  for (int kt = 0; kt < 1024; kt += 64) {
#pragma unroll
    for (int it = 0; it < 2; ++it) {
      int c = it * 256 + tid;
      int row = c >> 3, col = c & 7;
      gload_lds16(A + (size_t)(brow + row) * 1024 + kt + col * 8,
                  As + (size_t)(it * 256 + w * 64) * 8);
    }
#pragma unroll
    for (int it = 0; it < 4; ++it) {
      int c = it * 256 + tid;
      int row = c >> 3, col = c & 7;
      gload_lds16(Bt + (size_t)(bcol + row) * 1024 + kt + col * 8,
                  Bs + (size_t)(it * 256 + w * 64) * 8);
    }
    asm volatile("s_waitcnt vmcnt(0)" ::: "memory");
    __syncthreads();
    const bf16x8* As8 = reinterpret_cast<const bf16x8*>(As);
    const bf16x8* Bs8 = reinterpret_cast<const bf16x8*>(Bs);
#pragma unroll
    for (int ks = 0; ks < 2; ++ks) {
      bf16x8 af[2], bfv[4];
#pragma unroll
      for (int m = 0; m < 2; ++m)
        af[m] = As8[(size_t)(wm * 32 + m * 16 + lq) * 8 + ks * 4 + lg];
#pragma unroll
      for (int n = 0; n < 4; ++n)
        bfv[n] = Bs8[(size_t)(wn * 64 + n * 16 + lq) * 8 + ks * 4 + lg];
#pragma unroll
      for (int m = 0; m < 2; ++m)
#pragma unroll
        for (int n = 0; n < 4; ++n)
          acc[m][n] = mfma16(af[m], bfv[n], acc[m][n]);
    }
    __syncthreads();
  }

#pragma unroll
  for (int n = 0; n < 4; ++n) {
    int N = bcol + wn * 64 + n * 16 + lq;
    float bv = bias[N];
#pragma unroll
    for (int m = 0; m < 2; ++m) {
      int M0 = brow + wm * 32 + m * 16 + lg * 4;
#pragma unroll
      for (int r = 0; r < 4; ++r)
        outF[(size_t)(M0 + r) * 1024 + N] = acc[m][n][r] + bv;
    }
  }
}

// ---------------- flash attention: seq keys [0,2048), prefix tile at 2048 ---
// Paired 64-row q-tiles {pi, 31-pi}: uniform work; shared K/V staging stream.
// bh-major grid (per-head L2 locality). 4 waves x 16 q-rows per stream,
// KVBLK=64 double-buffered 2-phase prefetch. Swapped QK^T, log2-domain online
// softmax, lane-local l partials, rescale shfls only in rare branch (T13).
__global__ __launch_bounds__(256, 4) void k_attn(
    const unsigned short* __restrict__ Qb, const unsigned short* __restrict__ Kb,
    const unsigned short* __restrict__ Vt, unsigned short* __restrict__ O) {
  __shared__ unsigned short Ks[2][64 * 64];
  __shared__ unsigned short Vs[2][64 * 64];
  __shared__ unsigned short Ps[4][16 * 64];
  int tid = threadIdx.x;
  int w = tid >> 6, l = tid & 63;
  int lq = l & 15, lg = l >> 4;
  int bh = blockIdx.x;           // bh-major: head's blocks share an XCD
  int pi = blockIdx.y;           // 0..15
  int qtL = pi, qtH = 31 - pi;   // 64-row q-tile indices
  int ntot = qtH + 2;            // seq tiles 0..qtH, then the prefix tile
  int qsA[2] = {qtL * 64, qtH * 64};

  bf16x8 qf[2][2];
#pragma unroll
  for (int qt = 0; qt < 2; ++qt) {
    const unsigned short* Qg = Qb + ((size_t)bh * Sq + qsA[qt] + w * 16) * DK;
#pragma unroll
    for (int ks = 0; ks < 2; ++ks)
      qf[qt][ks] = *reinterpret_cast<const bf16x8*>(
          Qg + (size_t)lq * DK + ks * 32 + lg * 8);
  }

  const unsigned short* Kg = Kb + (size_t)bh * SKPAD * DK;
  const unsigned short* Vg = Vt + (size_t)bh * DK * SKPAD;

  float m_run[2] = {-1e30f, -1e30f};
  float l_part[2] = {0.f, 0.f};
  f32x4 oacc[2][4];
#pragma unroll
  for (int qt = 0; qt < 2; ++qt)
#pragma unroll
    for (int n = 0; n < 4; ++n) oacc[qt][n] = (f32x4){0.f, 0.f, 0.f, 0.f};

  unsigned short* Pw = &Ps[w][0];

  auto STAGE = [&](int b, int tile) {
    int kt = tile * 64;
#pragma unroll
    for (int it = 0; it < 2; ++it) {
      int dst = (it * 256 + tid) * 16;
      int srcK = dst ^ (((dst >> 7) & 7) << 4);
      gload_lds16((const char*)(Kg + (size_t)kt * DK) + srcK,
                  (char*)&Ks[b][0] + (size_t)(it * 256 + w * 64) * 16);
    }
#pragma unroll
    for (int it = 0; it < 2; ++it) {
      int dst = (it * 256 + tid) * 16;
      int row = dst >> 7;
      int colb = (dst & 127) ^ ((row & 7) << 4);
      gload_lds16((const char*)(Vg + (size_t)row * SKPAD + kt) + colb,
                  (char*)&Vs[b][0] + (size_t)(it * 256 + w * 64) * 16);
    }
  };

  STAGE(0, 0);
  asm volatile("s_waitcnt vmcnt(0)" ::: "memory");
  __syncthreads();

  for (int t = 0; t < ntot; ++t) {
    int bsel = t & 1;
    bool isLast = (t == ntot - 1);
    if (!isLast) STAGE(bsel ^ 1, (t + 1 == ntot - 1) ? (Sq / 64) : (t + 1));
    int kt = isLast ? Sq : t * 64;

#pragma unroll
    for (int qt = 0; qt < 2; ++qt) {
      int qs = qsA[qt];
      if (!isLast) {
        if (qt == 0 && t > qtL) continue;        // light stream: past its diagonal
        if (kt > qs + w * 16 + 15) continue;     // wave-uniform causal skip
      }

      // S^T = K*Q : D[key][q], col q = lq, rows key = m*16 + lg*4 + r
      f32x4 st[4];
#pragma unroll
      for (int m = 0; m < 4; ++m) st[m] = (f32x4){0.f, 0.f, 0.f, 0.f};
      __builtin_amdgcn_s_setprio(1);
#pragma unroll
      for (int ks = 0; ks < 2; ++ks) {
#pragma unroll
        for (int m = 0; m < 4; ++m) {
          if (isLast && m > 0) continue;         // prefix keys live in m=0 only
          int krow = m * 16 + lq;
          int byt = (krow * 128 + ks * 64 + lg * 16) ^ ((krow & 7) << 4);
          bf16x8 kf = *reinterpret_cast<const bf16x8*>((const char*)&Ks[bsel][0] + byt);
          st[m] = mfma16(kf, qf[qt][ks], st[m]);
        }
      }
      __builtin_amdgcn_s_setprio(0);

      if (isLast) {
        // prefix tile: key index m*16+lg*4+r visible iff < Pn
#pragma unroll
        for (int m = 0; m < 4; ++m)
#pragma unroll
          for (int r = 0; r < 4; ++r) {
            int ki = m * 16 + lg * 4 + r;
            st[m][r] = (ki < Pn) ? st[m][r] : -1e30f;
          }
      } else if (kt + 63 > qs + w * 16) {
        int qrow = qs + w * 16 + lq;
#pragma unroll
        for (int m = 0; m < 4; ++m)
#pragma unroll
          for (int r = 0; r < 4; ++r) {
            int key = kt + m * 16 + lg * 4 + r;
            st[m][r] = (key <= qrow) ? st[m][r] : -1e30f;
          }
      }

      float mx = fmaxf(fmaxf(st[0][0], st[0][1]), fmaxf(st[0][2], st[0][3]));
#pragma unroll
      for (int m = 1; m < 4; ++m)
        mx = fmaxf(mx, fmaxf(fmaxf(st[m][0], st[m][1]), fmaxf(st[m][2], st[m][3])));
      if (__any(mx > m_run[qt] + 8.f)) {   // T13 defer-rescale (rare path)
        float gmx = fmaxf(mx, __shfl_xor(mx, 16));
        gmx = fmaxf(gmx, __shfl_xor(gmx, 32));
        float mnew = fmaxf(m_run[qt], gmx);
        float alpha = exp2_fast(m_run[qt] - mnew);
        m_run[qt] = mnew;
        l_part[qt] *= alpha;
        float ar[4];
#pragma unroll
        for (int r = 0; r < 4; ++r) ar[r] = __shfl(alpha, lg * 4 + r);
#pragma unroll
        for (int n = 0; n < 4; ++n)
#pragma unroll
          for (int r = 0; r < 4; ++r) oacc[qt][n][r] *= ar[r];
      }
      float rs = 0.f;
#pragma unroll
      for (int m = 0; m < 4; ++m) {
        bf16x4 p4;
#pragma unroll
        for (int r = 0; r < 4; ++r) {
          float p = exp2_fast(st[m][r] - m_run[qt]);
          rs += p;
          p4[r] = (__bf16)p;
        }
        int byt = (lq * 128 + m * 32 + lg * 8) ^ ((lq & 7) << 4);
        *reinterpret_cast<bf16x4*>((char*)Pw + byt) = p4;
      }
      l_part[qt] += rs;

      // O[q][dv] += P[q][key] @ V[key][dv]
      __builtin_amdgcn_s_setprio(1);
#pragma unroll
      for (int ks = 0; ks < 2; ++ks) {
        if (isLast && ks == 1) continue;          // prefix P is zero past key 31
        int pbyt = (lq * 128 + ks * 64 + lg * 16) ^ ((lq & 7) << 4);
        bf16x8 pf = *reinterpret_cast<const bf16x8*>((const char*)Pw + pbyt);
#pragma unroll
        for (int n = 0; n < 4; ++n) {
          int dv = n * 16 + lq;
          int vbyt = (dv * 128 + ks * 64 + lg * 16) ^ ((dv & 7) << 4);
          bf16x8 vf = *reinterpret_cast<const bf16x8*>((const char*)&Vs[bsel][0] + vbyt);
          oacc[qt][n] = mfma16(pf, vf, oacc[qt][n]);
        }
      }
      __builtin_amdgcn_s_setprio(0);
    }
    asm volatile("s_waitcnt vmcnt(0)" ::: "memory");
    __syncthreads();
  }

  int b = bh >> 4, h = bh & 15;
#pragma unroll
  for (int qt = 0; qt < 2; ++qt) {
    float ls = l_part[qt];
    ls += __shfl_xor(ls, 16);
    ls += __shfl_xor(ls, 32);
    float lr[4];
#pragma unroll
    for (int r = 0; r < 4; ++r) lr[r] = 1.0f / __shfl(ls, lg * 4 + r);
#pragma unroll
    for (int n = 0; n < 4; ++n)
#pragma unroll
      for (int r = 0; r < 4; ++r) {
        int qrow2 = qsA[qt] + w * 16 + lg * 4 + r;
        size_t idx = ((size_t)b * Sq + qrow2) * Dd + h * DK + n * 16 + lq;
        O[idx] = f2bf(oacc[qt][n][r] * lr[r]);
      }
  }
}

extern "C" void kernel_launch(void* const* d_in, const int* in_sizes, int n_in,
                              void* d_out, int out_size, void* d_ws, size_t ws_size,
                              hipStream_t stream) {
  (void)in_sizes; (void)n_in; (void)out_size; (void)ws_size;
  const float* q  = (const float*)d_in[0];
  const float* k  = (const float*)d_in[1];
  const float* v  = (const float*)d_in[2];
  const float* Wq = (const float*)d_in[4];
  const float* bq = (const float*)d_in[5];
  const float* Wk = (const float*)d_in[6];
  const float* bk = (const float*)d_in[7];
  const float* Wv = (const float*)d_in[8];
  const float* bv = (const float*)d_in[9];
  const float* Wo = (const float*)d_in[10];
  const float* bo = (const float*)d_in[11];
  const float* pk = (const float*)d_in[12];
  const float* pv = (const float*)d_in[13];

  unsigned short* wsp = (unsigned short*)d_ws;
  size_t off = 0;
  auto take = [&](size_t elems) { unsigned short* p = wsp + off; off += elems; return p; };
  unsigned short* Ob  = take(8388608);
  unsigned short* wqt = take(1048576);
  unsigned short* wkt = take(1048576);
  unsigned short* wvt = take(1048576);
  unsigned short* wot = take(1048576);
  unsigned short* Qbf = take(8388608);
  unsigned short* KbB = take((size_t)NBH * SKPAD * DK);
  unsigned short* VtB = take((size_t)NBH * DK * SKPAD);
  float* outF = (float*)d_out;

  k_wt<<<dim3(32, 32, 4), dim3(32, 8), 0, stream>>>(Wq, Wk, Wv, Wo, wqt, wkt, wvt, wot);
  k_fill<<<64, 256, 0, stream>>>(pk, pv, KbB, VtB);
  // Q scale folds 1/sqrt(dk) AND log2(e) for the exp2-domain softmax
  k_gemm_qkv<<<1536, 256, 0, stream>>>(q, k, v, wqt, wkt, wvt,
                                       bq, bk, bv, Qbf, KbB, VtB,
                                       0.125f * LOG2E);
  k_attn<<<dim3(NBH, 16), 256, 0, stream>>>(Qbf, KbB, VtB, Ob);
  k_gemm_o<<<1024, 256, 0, stream>>>(Ob, wot, bo, outF);
}

// Round 18
// 185.505 us; speedup vs baseline: 2.2813x; 2.2813x over previous
//
#include <hip/hip_runtime.h>

typedef __bf16 bf16x8 __attribute__((ext_vector_type(8)));
typedef __bf16 bf16x4 __attribute__((ext_vector_type(4)));
typedef float f32x4 __attribute__((ext_vector_type(4)));

constexpr int Sq = 2048, Dd = 1024, Hn = 16, Pn = 10, DK = 64;
constexpr int SKPAD = 2112;   // key axis: [0,2048) seq, [2048,2058) prefix, pad to 2112
constexpr int NBH = 64;       // B*H
constexpr float LOG2E = 1.44269504088896340736f;

__device__ __forceinline__ float exp2_fast(float x) {
  return __builtin_amdgcn_exp2f(x);  // v_exp_f32 computes 2^x natively
}

__device__ __forceinline__ unsigned short f2bf(float f) {
  unsigned int u = __float_as_uint(f);
  u += 0x7fffu + ((u >> 16) & 1u);   // RNE
  return (unsigned short)(u >> 16);
}

__device__ __forceinline__ void gload_lds16(const void* g, void* l) {
  __builtin_amdgcn_global_load_lds(
      (const __attribute__((address_space(1))) void*)g,
      (__attribute__((address_space(3))) void*)l, 16, 0, 0);
}

__device__ __forceinline__ f32x4 mfma16(bf16x8 a, bf16x8 b, f32x4 c) {
  return __builtin_amdgcn_mfma_f32_16x16x32_bf16(a, b, c, 0, 0, 0);
}

// ---------------- W transpose + convert: Wt[n][k] = W[k][n] ----------------
__global__ void k_wt(const float* __restrict__ W0, const float* __restrict__ W1,
                     const float* __restrict__ W2, const float* __restrict__ W3,
                     unsigned short* __restrict__ T0, unsigned short* __restrict__ T1,
                     unsigned short* __restrict__ T2, unsigned short* __restrict__ T3) {
  __shared__ float tile[32][33];
  const float* W; unsigned short* T;
  switch (blockIdx.z) {
    case 0: W = W0; T = T0; break;
    case 1: W = W1; T = T1; break;
    case 2: W = W2; T = T2; break;
    default: W = W3; T = T3; break;
  }
  int n0 = blockIdx.x * 32, k0 = blockIdx.y * 32;
  int tx = threadIdx.x, ty = threadIdx.y;
  for (int r = ty; r < 32; r += 8)
    tile[r][tx] = W[(size_t)(k0 + r) * Dd + n0 + tx];
  __syncthreads();
  for (int r = ty; r < 32; r += 8)
    T[(size_t)(n0 + r) * Dd + k0 + tx] = f2bf(tile[tx][r]);
}

// ---------------- prefix K/V fill (at key slots 2048..2057) + zero pad -------
__global__ void k_fill(const float* __restrict__ pk, const float* __restrict__ pv,
                       unsigned short* __restrict__ Kb, unsigned short* __restrict__ Vt) {
  int bh = blockIdx.x;
  int h = bh & (Hn - 1);
  unsigned short* Kbh = Kb + (size_t)bh * SKPAD * DK;
  unsigned short* Vth = Vt + (size_t)bh * DK * SKPAD;
  for (int i = threadIdx.x; i < Pn * DK; i += blockDim.x) {
    int p = i >> 6, dk = i & 63;
    float kv = pk[((size_t)h * Pn + p) * DK + dk];
    float vv = pv[((size_t)h * Pn + p) * DK + dk];
    Kbh[(Sq + p) * DK + dk] = f2bf(kv);
    Vth[(size_t)dk * SKPAD + Sq + p] = f2bf(vv);
  }
  constexpr int ZR = SKPAD - (Pn + Sq);  // 54 zero rows/cols
  for (int i = threadIdx.x; i < ZR * DK; i += blockDim.x) {
    int r = i >> 6, c = i & 63;
    Kbh[(Sq + Pn + r) * DK + c] = 0;
    Vth[(size_t)c * SKPAD + (Sq + Pn + r)] = 0;
  }
}

// ---------------- QKV GEMM: C[8192,1024] = A_f32 @ Bt^T + bias ----------------
// R9-exact: A staged fp32 via global_load_lds into 32 KB swizzled LDS, fp32->
// bf16 fused into the LDS->reg fragment path; B bf16 via global_load_lds into
// 16 KB swizzled LDS. 48 KB LDS, 2-barrier K-loop (BK=64). XCD swizzle (T1).
// stream 0: Q -> [B,H,S,DK] (scale folded)   stream 1: K -> [B,H,SKPAD,DK]
// stream 2: V -> [B,H,DK,SKPAD] transposed, stored via LDS transpose.
__global__ __launch_bounds__(256, 3) void k_gemm_qkv(
    const float* __restrict__ Aq, const float* __restrict__ Ak,
    const float* __restrict__ Av,
    const unsigned short* __restrict__ Wq, const unsigned short* __restrict__ Wk,
    const unsigned short* __restrict__ Wv,
    const float* __restrict__ bq, const float* __restrict__ bk,
    const float* __restrict__ bv,
    unsigned short* __restrict__ Qo, unsigned short* __restrict__ Ko,
    unsigned short* __restrict__ Vo, float qscale) {
  __shared__ float Af[128 * 64];            // 32 KB fp32 A tile (swizzled)
  __shared__ unsigned short Bs[128 * 64];   // 16 KB bf16 B tile (swizzled)
  int bx0 = blockIdx.x;                     // 0..1535
  int orig = (bx0 & 7) * 192 + (bx0 >> 3);  // bijective XCD-chunked swizzle
  int stream = orig >> 9, within = orig & 511;

  const float* A32; const unsigned short* Bt; const float* bias;
  unsigned short* outB; float scale;
  switch (stream) {
    case 0:  A32 = Aq; Bt = Wq; bias = bq; outB = Qo; scale = qscale; break;
    case 1:  A32 = Ak; Bt = Wk; bias = bk; outB = Ko; scale = 1.f; break;
    default: A32 = Av; Bt = Wv; bias = bv; outB = Vo; scale = 1.f; break;
  }

  int tid = threadIdx.x;
  int w = tid >> 6, l = tid & 63;
  int lq = l & 15, lg = l >> 4;
  int tm = within >> 3, tn = within & 7;
  int brow = tm * 128, bcol = tn * 128;
  int wm = w >> 1, wn = w & 1;

  f32x4 acc[4][4];
#pragma unroll
  for (int m = 0; m < 4; ++m)
#pragma unroll
    for (int n = 0; n < 4; ++n) acc[m][n] = (f32x4){0.f, 0.f, 0.f, 0.f};

  for (int kt = 0; kt < 1024; kt += 64) {
    // A fp32: 8 chunks of 16B/lane; LDS linear, global source pre-swizzled
#pragma unroll
    for (int it = 0; it < 8; ++it) {
      int c = it * 256 + tid;
      int row = c >> 4;
      int cb = (c & 15) * 16;                    // byte-in-row (256 B rows)
      int sb = cb ^ ((row & 7) << 4);
      gload_lds16((const char*)(A32 + (size_t)(brow + row) * 1024 + kt) + sb,
                  (char*)Af + (size_t)(it * 256 + w * 64) * 16);
    }
    // B bf16: 4 chunks; same involution on 128 B rows
#pragma unroll
    for (int it = 0; it < 4; ++it) {
      int c = it * 256 + tid;
      int row = c >> 3;
      int cb = (c & 7) * 16;
      int sb = cb ^ ((row & 7) << 4);
      gload_lds16((const char*)(Bt + (size_t)(bcol + row) * 1024 + kt) + sb,
                  (char*)Bs + (size_t)(it * 256 + w * 64) * 16);
    }
    asm volatile("s_waitcnt vmcnt(0)" ::: "memory");
    __syncthreads();
#pragma unroll
    for (int ks = 0; ks < 2; ++ks) {
      bf16x8 af[4], bfv[4];
#pragma unroll
      for (int m = 0; m < 4; ++m) {
        int row = wm * 64 + m * 16 + lq;
        int b0 = row * 256 + ks * 128 + lg * 32;
        int sw = (row & 7) << 4;
        f32x4 a0 = *reinterpret_cast<const f32x4*>((const char*)Af + (b0 ^ sw));
        f32x4 a1 = *reinterpret_cast<const f32x4*>((const char*)Af + ((b0 + 16) ^ sw));
        bf16x8 v;
        v[0] = (__bf16)a0[0]; v[1] = (__bf16)a0[1];
        v[2] = (__bf16)a0[2]; v[3] = (__bf16)a0[3];
        v[4] = (__bf16)a1[0]; v[5] = (__bf16)a1[1];
        v[6] = (__bf16)a1[2]; v[7] = (__bf16)a1[3];
        af[m] = v;
      }
#pragma unroll
      for (int n = 0; n < 4; ++n) {
        int row = wn * 64 + n * 16 + lq;
        int byt = (row * 128 + ks * 64 + lg * 16) ^ ((row & 7) << 4);
        bfv[n] = *reinterpret_cast<const bf16x8*>((const char*)Bs + byt);
      }
#pragma unroll
      for (int m = 0; m < 4; ++m)
#pragma unroll
        for (int n = 0; n < 4; ++n)
          acc[m][n] = mfma16(af[m], bfv[n], acc[m][n]);
    }
    __syncthreads();
  }

  if (stream < 2) {
#pragma unroll
    for (int n = 0; n < 4; ++n) {
      int N = bcol + wn * 64 + n * 16 + lq;
      float bv = bias[N];
#pragma unroll
      for (int m = 0; m < 4; ++m) {
        int M0 = brow + wm * 64 + m * 16 + lg * 4;
#pragma unroll
        for (int r = 0; r < 4; ++r) {
          float val = (acc[m][n][r] + bv) * scale;
          int Mr = M0 + r;
          int b = Mr >> 11, s = Mr & 2047;
          int h = N >> 6, dk = N & 63;
          size_t idx;
          if (stream == 0) idx = (((size_t)(b * Hn + h)) * Sq + s) * DK + dk;
          else             idx = (((size_t)(b * Hn + h)) * SKPAD + s) * DK + dk;
          outB[idx] = f2bf(val);
        }
      }
    }
  } else {
    // V: transpose 128x128 tile through LDS, then coalesced 16B row stores.
    __syncthreads();                    // all LDS reads of Af/Bs done
    unsigned short* T = (unsigned short*)Af;  // 32 KB: [col(dv)][row(s)] xor-swz
#pragma unroll
    for (int n = 0; n < 4; ++n) {
      int col = wn * 64 + n * 16 + lq;
      float bv = bias[bcol + col];
      int sw = (col & 7) << 4;
#pragma unroll
      for (int m = 0; m < 4; ++m) {
        int row0 = wm * 64 + m * 16 + lg * 4;
        ushort4 p4;
        p4.x = f2bf(acc[m][n][0] + bv);
        p4.y = f2bf(acc[m][n][1] + bv);
        p4.z = f2bf(acc[m][n][2] + bv);
        p4.w = f2bf(acc[m][n][3] + bv);
        *reinterpret_cast<ushort4*>(&T[col * 128 + (row0 ^ sw)]) = p4;
      }
    }
    __syncthreads();
    int b = brow >> 11, s0 = brow & 2047;
    int col = tid >> 1;                 // dv index within block (0..127)
    int off = (tid & 1) * 64;           // s offset (0 or 64)
    int sw = (col & 7) << 4;
    int h = (bcol + col) >> 6, dk = (bcol + col) & 63;
    unsigned short* dst = Vo + (((size_t)(b * Hn + h)) * DK + dk) * SKPAD + s0 + off;
#pragma unroll
    for (int j = 0; j < 8; ++j) {
      int4 v = *reinterpret_cast<const int4*>(&T[col * 128 + ((off + j * 8) ^ sw)]);
      *reinterpret_cast<int4*>(dst + j * 8) = v;
    }
  }
}

// ---------------- O GEMM: out[8192,1024] = Ob @ Wot^T + bo (fp32 out) -------
// 64x128 tile: grid 1024 -> 4 blocks/CU. Both operands via global_load_lds,
// 24 KB LDS, 2-barrier template.
__global__ __launch_bounds__(256, 4) void k_gemm_o(
    const unsigned short* __restrict__ A, const unsigned short* __restrict__ Bt,
    const float* __restrict__ bias, float* __restrict__ outF) {
  __shared__ unsigned short As[64 * 64];     // 8 KB
  __shared__ unsigned short Bs[128 * 64];    // 16 KB
  int bx0 = blockIdx.x;                      // 0..1023
  int within = (bx0 & 7) * 128 + (bx0 >> 3); // bijective XCD-chunked swizzle
  int tid = threadIdx.x;
  int w = tid >> 6, l = tid & 63;
  int lq = l & 15, lg = l >> 4;
  int tm = within >> 3, tn = within & 7;
  int brow = tm * 64, bcol = tn * 128;
  int wm = w >> 1, wn = w & 1;

  f32x4 acc[2][4];
#pragma unroll
  for (int m = 0; m < 2; ++m)
#pragma unroll
    for (int n = 0; n < 4; ++n) acc[m][n] = (f32x4){0.f, 0.f, 0.f, 0.f};

  for (int kt = 0; kt < 1024; kt += 64) {
#pragma unroll
    for (int it = 0; it < 2; ++it) {
      int c = it * 256 + tid;
      int row = c >> 3, col = c & 7;
      gload_lds16(A + (size_t)(brow + row) * 1024 + kt + col * 8,
                  As + (size_t)(it * 256 + w * 64) * 8);
    }
#pragma unroll
    for (int it = 0; it < 4; ++it) {
      int c = it * 256 + tid;
      int row = c >> 3, col = c & 7;
      gload_lds16(Bt + (size_t)(bcol + row) * 1024 + kt + col * 8,
                  Bs + (size_t)(it * 256 + w * 64) * 8);
    }
    asm volatile("s_waitcnt vmcnt(0)" ::: "memory");
    __syncthreads();
    const bf16x8* As8 = reinterpret_cast<const bf16x8*>(As);
    const bf16x8* Bs8 = reinterpret_cast<const bf16x8*>(Bs);
#pragma unroll
    for (int ks = 0; ks < 2; ++ks) {
      bf16x8 af[2], bfv[4];
#pragma unroll
      for (int m = 0; m < 2; ++m)
        af[m] = As8[(size_t)(wm * 32 + m * 16 + lq) * 8 + ks * 4 + lg];
#pragma unroll
      for (int n = 0; n < 4; ++n)
        bfv[n] = Bs8[(size_t)(wn * 64 + n * 16 + lq) * 8 + ks * 4 + lg];
#pragma unroll
      for (int m = 0; m < 2; ++m)
#pragma unroll
        for (int n = 0; n < 4; ++n)
          acc[m][n] = mfma16(af[m], bfv[n], acc[m][n]);
    }
    __syncthreads();
  }

#pragma unroll
  for (int n = 0; n < 4; ++n) {
    int N = bcol + wn * 64 + n * 16 + lq;
    float bv = bias[N];
#pragma unroll
    for (int m = 0; m < 2; ++m) {
      int M0 = brow + wm * 32 + m * 16 + lg * 4;
#pragma unroll
      for (int r = 0; r < 4; ++r)
        outF[(size_t)(M0 + r) * 1024 + N] = acc[m][n][r] + bv;
    }
  }
}

// ---------------- flash attention: seq keys [0,2048), prefix tile at 2048 ---
// Paired 64-row q-tiles {pi, 31-pi}: uniform work; shared K/V staging stream.
// bh-major grid (per-head L2 locality). 4 waves x 16 q-rows per stream,
// KVBLK=64 double-buffered 2-phase prefetch. Swapped QK^T, log2-domain online
// softmax, lane-local l partials, rescale shfls only in rare branch (T13).
__global__ __launch_bounds__(256, 4) void k_attn(
    const unsigned short* __restrict__ Qb, const unsigned short* __restrict__ Kb,
    const unsigned short* __restrict__ Vt, unsigned short* __restrict__ O) {
  __shared__ unsigned short Ks[2][64 * 64];
  __shared__ unsigned short Vs[2][64 * 64];
  __shared__ unsigned short Ps[4][16 * 64];
  int tid = threadIdx.x;
  int w = tid >> 6, l = tid & 63;
  int lq = l & 15, lg = l >> 4;
  int bh = blockIdx.x;           // bh-major: head's blocks share an XCD
  int pi = blockIdx.y;           // 0..15
  int qtL = pi, qtH = 31 - pi;   // 64-row q-tile indices
  int ntot = qtH + 2;            // seq tiles 0..qtH, then the prefix tile
  int qsA[2] = {qtL * 64, qtH * 64};

  bf16x8 qf[2][2];
#pragma unroll
  for (int qt = 0; qt < 2; ++qt) {
    const unsigned short* Qg = Qb + ((size_t)bh * Sq + qsA[qt] + w * 16) * DK;
#pragma unroll
    for (int ks = 0; ks < 2; ++ks)
      qf[qt][ks] = *reinterpret_cast<const bf16x8*>(
          Qg + (size_t)lq * DK + ks * 32 + lg * 8);
  }

  const unsigned short* Kg = Kb + (size_t)bh * SKPAD * DK;
  const unsigned short* Vg = Vt + (size_t)bh * DK * SKPAD;

  float m_run[2] = {-1e30f, -1e30f};
  float l_part[2] = {0.f, 0.f};
  f32x4 oacc[2][4];
#pragma unroll
  for (int qt = 0; qt < 2; ++qt)
#pragma unroll
    for (int n = 0; n < 4; ++n) oacc[qt][n] = (f32x4){0.f, 0.f, 0.f, 0.f};

  unsigned short* Pw = &Ps[w][0];

  auto STAGE = [&](int b, int tile) {
    int kt = tile * 64;
#pragma unroll
    for (int it = 0; it < 2; ++it) {
      int dst = (it * 256 + tid) * 16;
      int srcK = dst ^ (((dst >> 7) & 7) << 4);
      gload_lds16((const char*)(Kg + (size_t)kt * DK) + srcK,
                  (char*)&Ks[b][0] + (size_t)(it * 256 + w * 64) * 16);
    }
#pragma unroll
    for (int it = 0; it < 2; ++it) {
      int dst = (it * 256 + tid) * 16;
      int row = dst >> 7;
      int colb = (dst & 127) ^ ((row & 7) << 4);
      gload_lds16((const char*)(Vg + (size_t)row * SKPAD + kt) + colb,
                  (char*)&Vs[b][0] + (size_t)(it * 256 + w * 64) * 16);
    }
  };

  STAGE(0, 0);
  asm volatile("s_waitcnt vmcnt(0)" ::: "memory");
  __syncthreads();

  for (int t = 0; t < ntot; ++t) {
    int bsel = t & 1;
    bool isLast = (t == ntot - 1);
    if (!isLast) STAGE(bsel ^ 1, (t + 1 == ntot - 1) ? (Sq / 64) : (t + 1));
    int kt = isLast ? Sq : t * 64;

#pragma unroll
    for (int qt = 0; qt < 2; ++qt) {
      int qs = qsA[qt];
      if (!isLast) {
        if (qt == 0 && t > qtL) continue;        // light stream: past its diagonal
        if (kt > qs + w * 16 + 15) continue;     // wave-uniform causal skip
      }

      // S^T = K*Q : D[key][q], col q = lq, rows key = m*16 + lg*4 + r
      f32x4 st[4];
#pragma unroll
      for (int m = 0; m < 4; ++m) st[m] = (f32x4){0.f, 0.f, 0.f, 0.f};
      __builtin_amdgcn_s_setprio(1);
#pragma unroll
      for (int ks = 0; ks < 2; ++ks) {
#pragma unroll
        for (int m = 0; m < 4; ++m) {
          if (isLast && m > 0) continue;         // prefix keys live in m=0 only
          int krow = m * 16 + lq;
          int byt = (krow * 128 + ks * 64 + lg * 16) ^ ((krow & 7) << 4);
          bf16x8 kf = *reinterpret_cast<const bf16x8*>((const char*)&Ks[bsel][0] + byt);
          st[m] = mfma16(kf, qf[qt][ks], st[m]);
        }
      }
      __builtin_amdgcn_s_setprio(0);

      if (isLast) {
        // prefix tile: key index m*16+lg*4+r visible iff < Pn
#pragma unroll
        for (int m = 0; m < 4; ++m)
#pragma unroll
          for (int r = 0; r < 4; ++r) {
            int ki = m * 16 + lg * 4 + r;
            st[m][r] = (ki < Pn) ? st[m][r] : -1e30f;
          }
      } else if (kt + 63 > qs + w * 16) {
        int qrow = qs + w * 16 + lq;
#pragma unroll
        for (int m = 0; m < 4; ++m)
#pragma unroll
          for (int r = 0; r < 4; ++r) {
            int key = kt + m * 16 + lg * 4 + r;
            st[m][r] = (key <= qrow) ? st[m][r] : -1e30f;
          }
      }

      float mx = fmaxf(fmaxf(st[0][0], st[0][1]), fmaxf(st[0][2], st[0][3]));
#pragma unroll
      for (int m = 1; m < 4; ++m)
        mx = fmaxf(mx, fmaxf(fmaxf(st[m][0], st[m][1]), fmaxf(st[m][2], st[m][3])));
      if (__any(mx > m_run[qt] + 8.f)) {   // T13 defer-rescale (rare path)
        float gmx = fmaxf(mx, __shfl_xor(mx, 16));
        gmx = fmaxf(gmx, __shfl_xor(gmx, 32));
        float mnew = fmaxf(m_run[qt], gmx);
        float alpha = exp2_fast(m_run[qt] - mnew);
        m_run[qt] = mnew;
        l_part[qt] *= alpha;
        float ar[4];
#pragma unroll
        for (int r = 0; r < 4; ++r) ar[r] = __shfl(alpha, lg * 4 + r);
#pragma unroll
        for (int n = 0; n < 4; ++n)
#pragma unroll
          for (int r = 0; r < 4; ++r) oacc[qt][n][r] *= ar[r];
      }
      float rs = 0.f;
#pragma unroll
      for (int m = 0; m < 4; ++m) {
        bf16x4 p4;
#pragma unroll
        for (int r = 0; r < 4; ++r) {
          float p = exp2_fast(st[m][r] - m_run[qt]);
          rs += p;
          p4[r] = (__bf16)p;
        }
        int byt = (lq * 128 + m * 32 + lg * 8) ^ ((lq & 7) << 4);
        *reinterpret_cast<bf16x4*>((char*)Pw + byt) = p4;
      }
      l_part[qt] += rs;

      // O[q][dv] += P[q][key] @ V[key][dv]
      __builtin_amdgcn_s_setprio(1);
#pragma unroll
      for (int ks = 0; ks < 2; ++ks) {
        if (isLast && ks == 1) continue;          // prefix P is zero past key 31
        int pbyt = (lq * 128 + ks * 64 + lg * 16) ^ ((lq & 7) << 4);
        bf16x8 pf = *reinterpret_cast<const bf16x8*>((const char*)Pw + pbyt);
#pragma unroll
        for (int n = 0; n < 4; ++n) {
          int dv = n * 16 + lq;
          int vbyt = (dv * 128 + ks * 64 + lg * 16) ^ ((dv & 7) << 4);
          bf16x8 vf = *reinterpret_cast<const bf16x8*>((const char*)&Vs[bsel][0] + vbyt);
          oacc[qt][n] = mfma16(pf, vf, oacc[qt][n]);
        }
      }
      __builtin_amdgcn_s_setprio(0);
    }
    asm volatile("s_waitcnt vmcnt(0)" ::: "memory");
    __syncthreads();
  }

  int b = bh >> 4, h = bh & 15;
#pragma unroll
  for (int qt = 0; qt < 2; ++qt) {
    float ls = l_part[qt];
    ls += __shfl_xor(ls, 16);
    ls += __shfl_xor(ls, 32);
    float lr[4];
#pragma unroll
    for (int r = 0; r < 4; ++r) lr[r] = 1.0f / __shfl(ls, lg * 4 + r);
#pragma unroll
    for (int n = 0; n < 4; ++n)
#pragma unroll
      for (int r = 0; r < 4; ++r) {
        int qrow2 = qsA[qt] + w * 16 + lg * 4 + r;
        size_t idx = ((size_t)b * Sq + qrow2) * Dd + h * DK + n * 16 + lq;
        O[idx] = f2bf(oacc[qt][n][r] * lr[r]);
      }
  }
}

extern "C" void kernel_launch(void* const* d_in, const int* in_sizes, int n_in,
                              void* d_out, int out_size, void* d_ws, size_t ws_size,
                              hipStream_t stream) {
  (void)in_sizes; (void)n_in; (void)out_size; (void)ws_size;
  const float* q  = (const float*)d_in[0];
  const float* k  = (const float*)d_in[1];
  const float* v  = (const float*)d_in[2];
  const float* Wq = (const float*)d_in[4];
  const float* bq = (const float*)d_in[5];
  const float* Wk = (const float*)d_in[6];
  const float* bk = (const float*)d_in[7];
  const float* Wv = (const float*)d_in[8];
  const float* bv = (const float*)d_in[9];
  const float* Wo = (const float*)d_in[10];
  const float* bo = (const float*)d_in[11];
  const float* pk = (const float*)d_in[12];
  const float* pv = (const float*)d_in[13];

  unsigned short* wsp = (unsigned short*)d_ws;
  size_t off = 0;
  auto take = [&](size_t elems) { unsigned short* p = wsp + off; off += elems; return p; };
  unsigned short* Ob  = take(8388608);
  unsigned short* wqt = take(1048576);
  unsigned short* wkt = take(1048576);
  unsigned short* wvt = take(1048576);
  unsigned short* wot = take(1048576);
  unsigned short* Qbf = take(8388608);
  unsigned short* KbB = take((size_t)NBH * SKPAD * DK);
  unsigned short* VtB = take((size_t)NBH * DK * SKPAD);
  float* outF = (float*)d_out;

  k_wt<<<dim3(32, 32, 4), dim3(32, 8), 0, stream>>>(Wq, Wk, Wv, Wo, wqt, wkt, wvt, wot);
  k_fill<<<64, 256, 0, stream>>>(pk, pv, KbB, VtB);
  // Q scale folds 1/sqrt(dk) AND log2(e) for the exp2-domain softmax
  k_gemm_qkv<<<1536, 256, 0, stream>>>(q, k, v, wqt, wkt, wvt,
                                       bq, bk, bv, Qbf, KbB, VtB,
                                       0.125f * LOG2E);
  k_attn<<<dim3(NBH, 16), 256, 0, stream>>>(Qbf, KbB, VtB, Ob);
  k_gemm_o<<<1024, 256, 0, stream>>>(Ob, wot, bo, outF);
}

// Round 19
// 184.418 us; speedup vs baseline: 2.2947x; 1.0059x over previous
//
#include <hip/hip_runtime.h>

typedef __bf16 bf16x8 __attribute__((ext_vector_type(8)));
typedef __bf16 bf16x4 __attribute__((ext_vector_type(4)));
typedef float f32x4 __attribute__((ext_vector_type(4)));

constexpr int Sq = 2048, Dd = 1024, Hn = 16, Pn = 10, DK = 64;
constexpr int SKPAD = 2112;   // key axis: [0,2048) seq, [2048,2058) prefix, pad to 2112
constexpr int NBH = 64;       // B*H
constexpr float LOG2E = 1.44269504088896340736f;

__device__ __forceinline__ float exp2_fast(float x) {
  return __builtin_amdgcn_exp2f(x);  // v_exp_f32 computes 2^x natively
}

__device__ __forceinline__ unsigned short f2bf(float f) {
  unsigned int u = __float_as_uint(f);
  u += 0x7fffu + ((u >> 16) & 1u);   // RNE
  return (unsigned short)(u >> 16);
}

__device__ __forceinline__ void gload_lds16(const void* g, void* l) {
  __builtin_amdgcn_global_load_lds(
      (const __attribute__((address_space(1))) void*)g,
      (__attribute__((address_space(3))) void*)l, 16, 0, 0);
}

__device__ __forceinline__ f32x4 mfma16(bf16x8 a, bf16x8 b, f32x4 c) {
  return __builtin_amdgcn_mfma_f32_16x16x32_bf16(a, b, c, 0, 0, 0);
}

// ------- prep: W transposes (blocks 0..4095) + prefix K/V fill (4096..4159) --
__global__ void k_prep(const float* __restrict__ W0, const float* __restrict__ W1,
                       const float* __restrict__ W2, const float* __restrict__ W3,
                       unsigned short* __restrict__ T0, unsigned short* __restrict__ T1,
                       unsigned short* __restrict__ T2, unsigned short* __restrict__ T3,
                       const float* __restrict__ pk, const float* __restrict__ pv,
                       unsigned short* __restrict__ Kb, unsigned short* __restrict__ Vt) {
  int bx = blockIdx.x;
  int tid = threadIdx.x;
  if (bx < 4096) {
    // W transpose + convert: Wt[n][k] = W[k][n]
    __shared__ float tile[32][33];
    int z = bx >> 10, rem = bx & 1023;
    const float* W; unsigned short* T;
    switch (z) {
      case 0: W = W0; T = T0; break;
      case 1: W = W1; T = T1; break;
      case 2: W = W2; T = T2; break;
      default: W = W3; T = T3; break;
    }
    int n0 = (rem & 31) * 32, k0 = (rem >> 5) * 32;
    int tx = tid & 31, ty = tid >> 5;   // 32 x 8
    for (int r = ty; r < 32; r += 8)
      tile[r][tx] = W[(size_t)(k0 + r) * Dd + n0 + tx];
    __syncthreads();
    for (int r = ty; r < 32; r += 8)
      T[(size_t)(n0 + r) * Dd + k0 + tx] = f2bf(tile[tx][r]);
  } else {
    // prefix K/V fill (at key slots 2048..2057) + zero pad
    int bh = bx - 4096;
    int h = bh & (Hn - 1);
    unsigned short* Kbh = Kb + (size_t)bh * SKPAD * DK;
    unsigned short* Vth = Vt + (size_t)bh * DK * SKPAD;
    for (int i = tid; i < Pn * DK; i += blockDim.x) {
      int p = i >> 6, dk = i & 63;
      float kv = pk[((size_t)h * Pn + p) * DK + dk];
      float vv = pv[((size_t)h * Pn + p) * DK + dk];
      Kbh[(Sq + p) * DK + dk] = f2bf(kv);
      Vth[(size_t)dk * SKPAD + Sq + p] = f2bf(vv);
    }
    constexpr int ZR = SKPAD - (Pn + Sq);  // 54 zero rows/cols
    for (int i = tid; i < ZR * DK; i += blockDim.x) {
      int r = i >> 6, c = i & 63;
      Kbh[(Sq + Pn + r) * DK + c] = 0;
      Vth[(size_t)c * SKPAD + (Sq + Pn + r)] = 0;
    }
  }
}

// ---------------- QKV GEMM: C[8192,1024] = A_f32 @ Bt^T + bias ----------------
// R9-exact: A staged fp32 via global_load_lds into 32 KB swizzled LDS, fp32->
// bf16 fused into the LDS->reg fragment path; B bf16 via global_load_lds into
// 16 KB swizzled LDS. 48 KB LDS, 2-barrier K-loop (BK=64). XCD swizzle (T1).
// stream 0: Q -> [B,H,S,DK] (scale folded)   stream 1: K -> [B,H,SKPAD,DK]
// stream 2: V -> [B,H,DK,SKPAD] transposed, stored via LDS transpose.
__global__ __launch_bounds__(256, 3) void k_gemm_qkv(
    const float* __restrict__ Aq, const float* __restrict__ Ak,
    const float* __restrict__ Av,
    const unsigned short* __restrict__ Wq, const unsigned short* __restrict__ Wk,
    const unsigned short* __restrict__ Wv,
    const float* __restrict__ bq, const float* __restrict__ bk,
    const float* __restrict__ bv,
    unsigned short* __restrict__ Qo, unsigned short* __restrict__ Ko,
    unsigned short* __restrict__ Vo, float qscale) {
  __shared__ float Af[128 * 64];            // 32 KB fp32 A tile (swizzled)
  __shared__ unsigned short Bs[128 * 64];   // 16 KB bf16 B tile (swizzled)
  int bx0 = blockIdx.x;                     // 0..1535
  int orig = (bx0 & 7) * 192 + (bx0 >> 3);  // bijective XCD-chunked swizzle
  int stream = orig >> 9, within = orig & 511;

  const float* A32; const unsigned short* Bt; const float* bias;
  unsigned short* outB; float scale;
  switch (stream) {
    case 0:  A32 = Aq; Bt = Wq; bias = bq; outB = Qo; scale = qscale; break;
    case 1:  A32 = Ak; Bt = Wk; bias = bk; outB = Ko; scale = 1.f; break;
    default: A32 = Av; Bt = Wv; bias = bv; outB = Vo; scale = 1.f; break;
  }

  int tid = threadIdx.x;
  int w = tid >> 6, l = tid & 63;
  int lq = l & 15, lg = l >> 4;
  int tm = within >> 3, tn = within & 7;
  int brow = tm * 128, bcol = tn * 128;
  int wm = w >> 1, wn = w & 1;

  f32x4 acc[4][4];
#pragma unroll
  for (int m = 0; m < 4; ++m)
#pragma unroll
    for (int n = 0; n < 4; ++n) acc[m][n] = (f32x4){0.f, 0.f, 0.f, 0.f};

  for (int kt = 0; kt < 1024; kt += 64) {
    // A fp32: 8 chunks of 16B/lane; LDS linear, global source pre-swizzled
#pragma unroll
    for (int it = 0; it < 8; ++it) {
      int c = it * 256 + tid;
      int row = c >> 4;
      int cb = (c & 15) * 16;                    // byte-in-row (256 B rows)
      int sb = cb ^ ((row & 7) << 4);
      gload_lds16((const char*)(A32 + (size_t)(brow + row) * 1024 + kt) + sb,
                  (char*)Af + (size_t)(it * 256 + w * 64) * 16);
    }
    // B bf16: 4 chunks; same involution on 128 B rows
#pragma unroll
    for (int it = 0; it < 4; ++it) {
      int c = it * 256 + tid;
      int row = c >> 3;
      int cb = (c & 7) * 16;
      int sb = cb ^ ((row & 7) << 4);
      gload_lds16((const char*)(Bt + (size_t)(bcol + row) * 1024 + kt) + sb,
                  (char*)Bs + (size_t)(it * 256 + w * 64) * 16);
    }
    asm volatile("s_waitcnt vmcnt(0)" ::: "memory");
    __syncthreads();
#pragma unroll
    for (int ks = 0; ks < 2; ++ks) {
      bf16x8 af[4], bfv[4];
#pragma unroll
      for (int m = 0; m < 4; ++m) {
        int row = wm * 64 + m * 16 + lq;
        int b0 = row * 256 + ks * 128 + lg * 32;
        int sw = (row & 7) << 4;
        f32x4 a0 = *reinterpret_cast<const f32x4*>((const char*)Af + (b0 ^ sw));
        f32x4 a1 = *reinterpret_cast<const f32x4*>((const char*)Af + ((b0 + 16) ^ sw));
        bf16x8 v;
        v[0] = (__bf16)a0[0]; v[1] = (__bf16)a0[1];
        v[2] = (__bf16)a0[2]; v[3] = (__bf16)a0[3];
        v[4] = (__bf16)a1[0]; v[5] = (__bf16)a1[1];
        v[6] = (__bf16)a1[2]; v[7] = (__bf16)a1[3];
        af[m] = v;
      }
#pragma unroll
      for (int n = 0; n < 4; ++n) {
        int row = wn * 64 + n * 16 + lq;
        int byt = (row * 128 + ks * 64 + lg * 16) ^ ((row & 7) << 4);
        bfv[n] = *reinterpret_cast<const bf16x8*>((const char*)Bs + byt);
      }
#pragma unroll
      for (int m = 0; m < 4; ++m)
#pragma unroll
        for (int n = 0; n < 4; ++n)
          acc[m][n] = mfma16(af[m], bfv[n], acc[m][n]);
    }
    __syncthreads();
  }

  if (stream < 2) {
#pragma unroll
    for (int n = 0; n < 4; ++n) {
      int N = bcol + wn * 64 + n * 16 + lq;
      float bv = bias[N];
#pragma unroll
      for (int m = 0; m < 4; ++m) {
        int M0 = brow + wm * 64 + m * 16 + lg * 4;
#pragma unroll
        for (int r = 0; r < 4; ++r) {
          float val = (acc[m][n][r] + bv) * scale;
          int Mr = M0 + r;
          int b = Mr >> 11, s = Mr & 2047;
          int h = N >> 6, dk = N & 63;
          size_t idx;
          if (stream == 0) idx = (((size_t)(b * Hn + h)) * Sq + s) * DK + dk;
          else             idx = (((size_t)(b * Hn + h)) * SKPAD + s) * DK + dk;
          outB[idx] = f2bf(val);
        }
      }
    }
  } else {
    // V: transpose 128x128 tile through LDS, then coalesced 16B row stores.
    __syncthreads();                    // all LDS reads of Af/Bs done
    unsigned short* T = (unsigned short*)Af;  // 32 KB: [col(dv)][row(s)] xor-swz
#pragma unroll
    for (int n = 0; n < 4; ++n) {
      int col = wn * 64 + n * 16 + lq;
      float bv = bias[bcol + col];
      int sw = (col & 7) << 4;
#pragma unroll
      for (int m = 0; m < 4; ++m) {
        int row0 = wm * 64 + m * 16 + lg * 4;
        ushort4 p4;
        p4.x = f2bf(acc[m][n][0] + bv);
        p4.y = f2bf(acc[m][n][1] + bv);
        p4.z = f2bf(acc[m][n][2] + bv);
        p4.w = f2bf(acc[m][n][3] + bv);
        *reinterpret_cast<ushort4*>(&T[col * 128 + (row0 ^ sw)]) = p4;
      }
    }
    __syncthreads();
    int b = brow >> 11, s0 = brow & 2047;
    int col = tid >> 1;                 // dv index within block (0..127)
    int off = (tid & 1) * 64;           // s offset (0 or 64)
    int sw = (col & 7) << 4;
    int h = (bcol + col) >> 6, dk = (bcol + col) & 63;
    unsigned short* dst = Vo + (((size_t)(b * Hn + h)) * DK + dk) * SKPAD + s0 + off;
#pragma unroll
    for (int j = 0; j < 8; ++j) {
      int4 v = *reinterpret_cast<const int4*>(&T[col * 128 + ((off + j * 8) ^ sw)]);
      *reinterpret_cast<int4*>(dst + j * 8) = v;
    }
  }
}

// ---------------- O GEMM: out[8192,1024] = Ob @ Wot^T + bo (fp32 out) -------
// 64x128 tile: grid 1024 -> 4 blocks/CU. Both operands via global_load_lds,
// 24 KB LDS, 2-barrier template.
__global__ __launch_bounds__(256, 4) void k_gemm_o(
    const unsigned short* __restrict__ A, const unsigned short* __restrict__ Bt,
    const float* __restrict__ bias, float* __restrict__ outF) {
  __shared__ unsigned short As[64 * 64];     // 8 KB
  __shared__ unsigned short Bs[128 * 64];    // 16 KB
  int bx0 = blockIdx.x;                      // 0..1023
  int within = (bx0 & 7) * 128 + (bx0 >> 3); // bijective XCD-chunked swizzle
  int tid = threadIdx.x;
  int w = tid >> 6, l = tid & 63;
  int lq = l & 15, lg = l >> 4;
  int tm = within >> 3, tn = within & 7;
  int brow = tm * 64, bcol = tn * 128;
  int wm = w >> 1, wn = w & 1;

  f32x4 acc[2][4];
#pragma unroll
  for (int m = 0; m < 2; ++m)
#pragma unroll
    for (int n = 0; n < 4; ++n) acc[m][n] = (f32x4){0.f, 0.f, 0.f, 0.f};

  for (int kt = 0; kt < 1024; kt += 64) {
#pragma unroll
    for (int it = 0; it < 2; ++it) {
      int c = it * 256 + tid;
      int row = c >> 3, col = c & 7;
      gload_lds16(A + (size_t)(brow + row) * 1024 + kt + col * 8,
                  As + (size_t)(it * 256 + w * 64) * 8);
    }
#pragma unroll
    for (int it = 0; it < 4; ++it) {
      int c = it * 256 + tid;
      int row = c >> 3, col = c & 7;
      gload_lds16(Bt + (size_t)(bcol + row) * 1024 + kt + col * 8,
                  Bs + (size_t)(it * 256 + w * 64) * 8);
    }
    asm volatile("s_waitcnt vmcnt(0)" ::: "memory");
    __syncthreads();
    const bf16x8* As8 = reinterpret_cast<const bf16x8*>(As);
    const bf16x8* Bs8 = reinterpret_cast<const bf16x8*>(Bs);
#pragma unroll
    for (int ks = 0; ks < 2; ++ks) {
      bf16x8 af[2], bfv[4];
#pragma unroll
      for (int m = 0; m < 2; ++m)
        af[m] = As8[(size_t)(wm * 32 + m * 16 + lq) * 8 + ks * 4 + lg];
#pragma unroll
      for (int n = 0; n < 4; ++n)
        bfv[n] = Bs8[(size_t)(wn * 64 + n * 16 + lq) * 8 + ks * 4 + lg];
#pragma unroll
      for (int m = 0; m < 2; ++m)
#pragma unroll
        for (int n = 0; n < 4; ++n)
          acc[m][n] = mfma16(af[m], bfv[n], acc[m][n]);
    }
    __syncthreads();
  }

#pragma unroll
  for (int n = 0; n < 4; ++n) {
    int N = bcol + wn * 64 + n * 16 + lq;
    float bv = bias[N];
#pragma unroll
    for (int m = 0; m < 2; ++m) {
      int M0 = brow + wm * 32 + m * 16 + lg * 4;
#pragma unroll
      for (int r = 0; r < 4; ++r)
        outF[(size_t)(M0 + r) * 1024 + N] = acc[m][n][r] + bv;
    }
  }
}

// ---------------- flash attention: seq keys [0,2048), prefix tile at 2048 ---
// Paired 64-row q-tiles {pi, 31-pi}: uniform work; shared K/V staging stream.
// bh-major grid (per-head L2 locality). 4 waves x 16 q-rows per stream,
// KVBLK=64 double-buffered 2-phase prefetch. Swapped QK^T, log2-domain online
// softmax, lane-local l partials, rescale shfls only in rare branch (T13).
__global__ __launch_bounds__(256, 4) void k_attn(
    const unsigned short* __restrict__ Qb, const unsigned short* __restrict__ Kb,
    const unsigned short* __restrict__ Vt, unsigned short* __restrict__ O) {
  __shared__ unsigned short Ks[2][64 * 64];
  __shared__ unsigned short Vs[2][64 * 64];
  __shared__ unsigned short Ps[4][16 * 64];
  int tid = threadIdx.x;
  int w = tid >> 6, l = tid & 63;
  int lq = l & 15, lg = l >> 4;
  int bh = blockIdx.x;           // bh-major: head's blocks share an XCD
  int pi = blockIdx.y;           // 0..15
  int qtL = pi, qtH = 31 - pi;   // 64-row q-tile indices
  int ntot = qtH + 2;            // seq tiles 0..qtH, then the prefix tile
  int qsA[2] = {qtL * 64, qtH * 64};

  bf16x8 qf[2][2];
#pragma unroll
  for (int qt = 0; qt < 2; ++qt) {
    const unsigned short* Qg = Qb + ((size_t)bh * Sq + qsA[qt] + w * 16) * DK;
#pragma unroll
    for (int ks = 0; ks < 2; ++ks)
      qf[qt][ks] = *reinterpret_cast<const bf16x8*>(
          Qg + (size_t)lq * DK + ks * 32 + lg * 8);
  }

  const unsigned short* Kg = Kb + (size_t)bh * SKPAD * DK;
  const unsigned short* Vg = Vt + (size_t)bh * DK * SKPAD;

  float m_run[2] = {-1e30f, -1e30f};
  float l_part[2] = {0.f, 0.f};
  f32x4 oacc[2][4];
#pragma unroll
  for (int qt = 0; qt < 2; ++qt)
#pragma unroll
    for (int n = 0; n < 4; ++n) oacc[qt][n] = (f32x4){0.f, 0.f, 0.f, 0.f};

  unsigned short* Pw = &Ps[w][0];

  auto STAGE = [&](int b, int tile) {
    int kt = tile * 64;
#pragma unroll
    for (int it = 0; it < 2; ++it) {
      int dst = (it * 256 + tid) * 16;
      int srcK = dst ^ (((dst >> 7) & 7) << 4);
      gload_lds16((const char*)(Kg + (size_t)kt * DK) + srcK,
                  (char*)&Ks[b][0] + (size_t)(it * 256 + w * 64) * 16);
    }
#pragma unroll
    for (int it = 0; it < 2; ++it) {
      int dst = (it * 256 + tid) * 16;
      int row = dst >> 7;
      int colb = (dst & 127) ^ ((row & 7) << 4);
      gload_lds16((const char*)(Vg + (size_t)row * SKPAD + kt) + colb,
                  (char*)&Vs[b][0] + (size_t)(it * 256 + w * 64) * 16);
    }
  };

  STAGE(0, 0);
  asm volatile("s_waitcnt vmcnt(0)" ::: "memory");
  __syncthreads();

  for (int t = 0; t < ntot; ++t) {
    int bsel = t & 1;
    bool isLast = (t == ntot - 1);
    if (!isLast) STAGE(bsel ^ 1, (t + 1 == ntot - 1) ? (Sq / 64) : (t + 1));
    int kt = isLast ? Sq : t * 64;

#pragma unroll
    for (int qt = 0; qt < 2; ++qt) {
      int qs = qsA[qt];
      if (!isLast) {
        if (qt == 0 && t > qtL) continue;        // light stream: past its diagonal
        if (kt > qs + w * 16 + 15) continue;     // wave-uniform causal skip
      }

      // S^T = K*Q : D[key][q], col q = lq, rows key = m*16 + lg*4 + r
      f32x4 st[4];
#pragma unroll
      for (int m = 0; m < 4; ++m) st[m] = (f32x4){0.f, 0.f, 0.f, 0.f};
      __builtin_amdgcn_s_setprio(1);
#pragma unroll
      for (int ks = 0; ks < 2; ++ks) {
#pragma unroll
        for (int m = 0; m < 4; ++m) {
          if (isLast && m > 0) continue;         // prefix keys live in m=0 only
          int krow = m * 16 + lq;
          int byt = (krow * 128 + ks * 64 + lg * 16) ^ ((krow & 7) << 4);
          bf16x8 kf = *reinterpret_cast<const bf16x8*>((const char*)&Ks[bsel][0] + byt);
          st[m] = mfma16(kf, qf[qt][ks], st[m]);
        }
      }
      __builtin_amdgcn_s_setprio(0);

      if (isLast) {
        // prefix tile: key index m*16+lg*4+r visible iff < Pn
#pragma unroll
        for (int m = 0; m < 4; ++m)
#pragma unroll
          for (int r = 0; r < 4; ++r) {
            int ki = m * 16 + lg * 4 + r;
            st[m][r] = (ki < Pn) ? st[m][r] : -1e30f;
          }
      } else if (kt + 63 > qs + w * 16) {
        int qrow = qs + w * 16 + lq;
#pragma unroll
        for (int m = 0; m < 4; ++m)
#pragma unroll
          for (int r = 0; r < 4; ++r) {
            int key = kt + m * 16 + lg * 4 + r;
            st[m][r] = (key <= qrow) ? st[m][r] : -1e30f;
          }
      }

      float mx = fmaxf(fmaxf(st[0][0], st[0][1]), fmaxf(st[0][2], st[0][3]));
#pragma unroll
      for (int m = 1; m < 4; ++m)
        mx = fmaxf(mx, fmaxf(fmaxf(st[m][0], st[m][1]), fmaxf(st[m][2], st[m][3])));
      if (__any(mx > m_run[qt] + 8.f)) {   // T13 defer-rescale (rare path)
        float gmx = fmaxf(mx, __shfl_xor(mx, 16));
        gmx = fmaxf(gmx, __shfl_xor(gmx, 32));
        float mnew = fmaxf(m_run[qt], gmx);
        float alpha = exp2_fast(m_run[qt] - mnew);
        m_run[qt] = mnew;
        l_part[qt] *= alpha;
        float ar[4];
#pragma unroll
        for (int r = 0; r < 4; ++r) ar[r] = __shfl(alpha, lg * 4 + r);
#pragma unroll
        for (int n = 0; n < 4; ++n)
#pragma unroll
          for (int r = 0; r < 4; ++r) oacc[qt][n][r] *= ar[r];
      }
      float rs = 0.f;
#pragma unroll
      for (int m = 0; m < 4; ++m) {
        bf16x4 p4;
#pragma unroll
        for (int r = 0; r < 4; ++r) {
          float p = exp2_fast(st[m][r] - m_run[qt]);
          rs += p;
          p4[r] = (__bf16)p;
        }
        int byt = (lq * 128 + m * 32 + lg * 8) ^ ((lq & 7) << 4);
        *reinterpret_cast<bf16x4*>((char*)Pw + byt) = p4;
      }
      l_part[qt] += rs;

      // O[q][dv] += P[q][key] @ V[key][dv]
      __builtin_amdgcn_s_setprio(1);
#pragma unroll
      for (int ks = 0; ks < 2; ++ks) {
        if (isLast && ks == 1) continue;          // prefix P is zero past key 31
        int pbyt = (lq * 128 + ks * 64 + lg * 16) ^ ((lq & 7) << 4);
        bf16x8 pf = *reinterpret_cast<const bf16x8*>((const char*)Pw + pbyt);
#pragma unroll
        for (int n = 0; n < 4; ++n) {
          int dv = n * 16 + lq;
          int vbyt = (dv * 128 + ks * 64 + lg * 16) ^ ((dv & 7) << 4);
          bf16x8 vf = *reinterpret_cast<const bf16x8*>((const char*)&Vs[bsel][0] + vbyt);
          oacc[qt][n] = mfma16(pf, vf, oacc[qt][n]);
        }
      }
      __builtin_amdgcn_s_setprio(0);
    }
    asm volatile("s_waitcnt vmcnt(0)" ::: "memory");
    __syncthreads();
  }

  int b = bh >> 4, h = bh & 15;
#pragma unroll
  for (int qt = 0; qt < 2; ++qt) {
    float ls = l_part[qt];
    ls += __shfl_xor(ls, 16);
    ls += __shfl_xor(ls, 32);
    float lr[4];
#pragma unroll
    for (int r = 0; r < 4; ++r) lr[r] = 1.0f / __shfl(ls, lg * 4 + r);
#pragma unroll
    for (int n = 0; n < 4; ++n)
#pragma unroll
      for (int r = 0; r < 4; ++r) {
        int qrow2 = qsA[qt] + w * 16 + lg * 4 + r;
        size_t idx = ((size_t)b * Sq + qrow2) * Dd + h * DK + n * 16 + lq;
        O[idx] = f2bf(oacc[qt][n][r] * lr[r]);
      }
  }
}

extern "C" void kernel_launch(void* const* d_in, const int* in_sizes, int n_in,
                              void* d_out, int out_size, void* d_ws, size_t ws_size,
                              hipStream_t stream) {
  (void)in_sizes; (void)n_in; (void)out_size; (void)ws_size;
  const float* q  = (const float*)d_in[0];
  const float* k  = (const float*)d_in[1];
  const float* v  = (const float*)d_in[2];
  const float* Wq = (const float*)d_in[4];
  const float* bq = (const float*)d_in[5];
  const float* Wk = (const float*)d_in[6];
  const float* bk = (const float*)d_in[7];
  const float* Wv = (const float*)d_in[8];
  const float* bv = (const float*)d_in[9];
  const float* Wo = (const float*)d_in[10];
  const float* bo = (const float*)d_in[11];
  const float* pk = (const float*)d_in[12];
  const float* pv = (const float*)d_in[13];

  unsigned short* wsp = (unsigned short*)d_ws;
  size_t off = 0;
  auto take = [&](size_t elems) { unsigned short* p = wsp + off; off += elems; return p; };
  unsigned short* Ob  = take(8388608);
  unsigned short* wqt = take(1048576);
  unsigned short* wkt = take(1048576);
  unsigned short* wvt = take(1048576);
  unsigned short* wot = take(1048576);
  unsigned short* Qbf = take(8388608);
  unsigned short* KbB = take((size_t)NBH * SKPAD * DK);
  unsigned short* VtB = take((size_t)NBH * DK * SKPAD);
  float* outF = (float*)d_out;

  k_prep<<<4096 + NBH, 256, 0, stream>>>(Wq, Wk, Wv, Wo, wqt, wkt, wvt, wot,
                                         pk, pv, KbB, VtB);
  // Q scale folds 1/sqrt(dk) AND log2(e) for the exp2-domain softmax
  k_gemm_qkv<<<1536, 256, 0, stream>>>(q, k, v, wqt, wkt, wvt,
                                       bq, bk, bv, Qbf, KbB, VtB,
                                       0.125f * LOG2E);
  k_attn<<<dim3(NBH, 16), 256, 0, stream>>>(Qbf, KbB, VtB, Ob);
  k_gemm_o<<<1024, 256, 0, stream>>>(Ob, wot, bo, outF);
}